// Round 6
// baseline (3168.483 us; speedup 1.0000x reference)
//
#include <hip/hip_runtime.h>
#include <hip/hip_bf16.h>
#include <cstdint>
#include <cstddef>

#define BB 256
#define TT 3000
#define II 40
#define HH 64

typedef float f32x4_t __attribute__((ext_vector_type(4)));
typedef short bf16x8_t __attribute__((ext_vector_type(8)));

__device__ __forceinline__ float sigmoidf_(float x) {
  return __fdividef(1.0f, 1.0f + __expf(-x));
}
__device__ __forceinline__ float tanhf_(float x) {
  float t = __expf(2.0f * x);
  return 1.0f - __fdividef(2.0f, t + 1.0f);
}
__device__ __forceinline__ unsigned cvtpk(float lo, float hi) {
  unsigned r;
  asm("v_cvt_pk_bf16_f32 %0, %1, %2" : "=v"(r) : "v"(lo), "v"(hi));
  return r;
}
union U8 { unsigned u[4]; bf16x8_t v; };
__device__ __forceinline__ bf16x8_t pack8(float a0, float a1, float a2, float a3,
                                          float b0, float b1, float b2, float b3) {
  U8 t;
  t.u[0] = cvtpk(a0, a1);
  t.u[1] = cvtpk(a2, a3);
  t.u[2] = cvtpk(b0, b1);
  t.u[3] = cvtpk(b2, b3);
  return t.v;
}
__device__ __forceinline__ float bf16bits_lo(unsigned u) { return __uint_as_float(u << 16); }
__device__ __forceinline__ float bf16bits_hi(unsigned u) { return __uint_as_float(u & 0xFFFF0000u); }

// MFMA-batched biLSTM scan. One block = one group of 16 sequences (same dir).
// 4 waves; wave wv owns M-tiles {wv, wv+4, wv+8, wv+12} => all 4 gate types
// (i,f,g,o) for cells 16wv..16wv+15 land in-lane (C layout: col=lane&15=seq,
// row=4*(lane>>4)+reg). K = [x(40, zero-padded); h(64)] via 4 K-tiles of 32.
// A-frag (16x16x32 bf16): row = lane&15, k = 4*(lane>>4) + (j&3) + 16*(j>>2).
// B-frag: col = lane&15, same k mapping. h exchanged via 4.6KB LDS parity
// buffer; ONE lgkmcnt-only barrier per step; x prefetched 2 steps ahead.
template <int SDIR>
__device__ __forceinline__ void scan_dir(
    const float* __restrict__ x,
    const float* __restrict__ W_ih, const float* __restrict__ W_hh,
    const float* __restrict__ b_ih, const float* __restrict__ b_hh,
    __hip_bfloat16* __restrict__ hcat, int dir, int gbase,
    short (*hx)[16][72]) {
  const int tid = threadIdx.x;
  const int l   = tid & 63;
  const int wv  = tid >> 6;      // wave 0..3
  const int g   = l >> 4;        // k-group / C-row-group (0..3)
  const int s   = l & 15;        // seq-within-group = A-row = C-col
  const int seq = gbase + s;
  const int b   = seq & (BB - 1);

  // ---- A fragments (weights, bf16) + bias ----
  bf16x8_t Ah[4][2], Ax[4][2];
  f32x4_t bias4[4];
#pragma unroll
  for (int gt = 0; gt < 4; ++gt) {
    const int R = 16 * (wv + 4 * gt) + s;  // gate row for A (row = lane&15)
    const float* wh = W_hh + (size_t)R * HH;
    {
      f32x4_t lo = *(const f32x4_t*)(wh + 4 * g);
      f32x4_t hi = *(const f32x4_t*)(wh + 16 + 4 * g);
      Ah[gt][0] = pack8(lo[0], lo[1], lo[2], lo[3], hi[0], hi[1], hi[2], hi[3]);
      f32x4_t lo2 = *(const f32x4_t*)(wh + 32 + 4 * g);
      f32x4_t hi2 = *(const f32x4_t*)(wh + 48 + 4 * g);
      Ah[gt][1] = pack8(lo2[0], lo2[1], lo2[2], lo2[3], hi2[0], hi2[1], hi2[2], hi2[3]);
    }
    const float* wi = W_ih + (size_t)R * II;
    {
      f32x4_t lo = *(const f32x4_t*)(wi + 4 * g);
      f32x4_t hi = *(const f32x4_t*)(wi + 16 + 4 * g);
      Ax[gt][0] = pack8(lo[0], lo[1], lo[2], lo[3], hi[0], hi[1], hi[2], hi[3]);
      // kt1: k = 32+4g (+j), valid only g<2; hi half (k>=48) always zero
      f32x4_t lo2;
      if (g < 2) lo2 = *(const f32x4_t*)(wi + 32 + 4 * g);
      else { lo2[0] = 0.f; lo2[1] = 0.f; lo2[2] = 0.f; lo2[3] = 0.f; }
      Ax[gt][1] = pack8(lo2[0], lo2[1], lo2[2], lo2[3], 0.f, 0.f, 0.f, 0.f);
    }
    // bias for acc regs: C row = 4*g + r within tile
#pragma unroll
    for (int r = 0; r < 4; ++r) {
      const int Rg = 16 * (wv + 4 * gt) + 4 * g + r;
      bias4[gt][r] = b_ih[Rg] + b_hh[Rg];
    }
  }

  // ---- per-step pointers ----
  const int t0 = (SDIR > 0) ? 0 : (TT - 1);
  const float* xrow = x + (size_t)b * TT * II + (size_t)t0 * II;
  const float* vA = xrow + 4 * g;                       // kt0 pieces: +0, +16
  const float* vB = xrow + ((g == 1) ? 36 : 32);        // kt1 piece (clamped)
  __hip_bfloat16* hp = hcat + ((size_t)b * TT + t0) * 128 + dir * HH + 16 * wv + 4 * g;

  // ---- x prefetch slots (2 steps ahead) ----
  f32x4_t Xa0 = *(const f32x4_t*)(vA);
  f32x4_t Xb0 = *(const f32x4_t*)(vA + 16);
  f32x4_t Xc0 = *(const f32x4_t*)(vB);
  f32x4_t Xa1 = *(const f32x4_t*)(vA + SDIR * II);
  f32x4_t Xb1 = *(const f32x4_t*)(vA + 16 + SDIR * II);
  f32x4_t Xc1 = *(const f32x4_t*)(vB + SDIR * II);

  f32x4_t c4; c4[0] = 0.f; c4[1] = 0.f; c4[2] = 0.f; c4[3] = 0.f;
  bf16x8_t bh0 = {0, 0, 0, 0, 0, 0, 0, 0};
  bf16x8_t bh1 = {0, 0, 0, 0, 0, 0, 0, 0};

#define BODY(T_, P_, XA_, XB_, XC_)                                            \
  do {                                                                         \
    const int t_ = (T_);                                                       \
    /* convert x slot to B-frags (kt1 hi half: reuse finite data, A=0) */      \
    bf16x8_t bx0 = pack8(XA_[0], XA_[1], XA_[2], XA_[3],                       \
                         XB_[0], XB_[1], XB_[2], XB_[3]);                      \
    bf16x8_t bx1 = pack8(XC_[0], XC_[1], XC_[2], XC_[3],                       \
                         XC_[0], XC_[1], XC_[2], XC_[3]);                      \
    /* reissue slot for t+2 */                                                 \
    if (t_ + 2 < TT) {                                                         \
      XA_ = *(const f32x4_t*)(vA + 2 * SDIR * II);                             \
      XB_ = *(const f32x4_t*)(vA + 16 + 2 * SDIR * II);                        \
      XC_ = *(const f32x4_t*)(vB + 2 * SDIR * II);                             \
    }                                                                          \
    /* gates = bias + W.[x;h] */                                               \
    f32x4_t acc[4];                                                            \
    _Pragma("unroll")                                                          \
    for (int gt = 0; gt < 4; ++gt) {                                           \
      acc[gt] = bias4[gt];                                                     \
      acc[gt] = __builtin_amdgcn_mfma_f32_16x16x32_bf16(Ax[gt][0], bx0, acc[gt], 0, 0, 0); \
      acc[gt] = __builtin_amdgcn_mfma_f32_16x16x32_bf16(Ax[gt][1], bx1, acc[gt], 0, 0, 0); \
      acc[gt] = __builtin_amdgcn_mfma_f32_16x16x32_bf16(Ah[gt][0], bh0, acc[gt], 0, 0, 0); \
      acc[gt] = __builtin_amdgcn_mfma_f32_16x16x32_bf16(Ah[gt][1], bh1, acc[gt], 0, 0, 0); \
    }                                                                          \
    /* activations + cell update (4 cells/lane, fully in-lane) */              \
    float hj[4];                                                               \
    _Pragma("unroll")                                                          \
    for (int j = 0; j < 4; ++j) {                                              \
      float gi = sigmoidf_(acc[0][j]);                                         \
      float gf = sigmoidf_(acc[1][j]);                                         \
      float gg = tanhf_(acc[2][j]);                                            \
      float go = sigmoidf_(acc[3][j]);                                         \
      c4[j] = fmaf(gf, c4[j], gi * gg);                                        \
      hj[j] = go * tanhf_(c4[j]);                                              \
    }                                                                          \
    uint2 hu;                                                                  \
    hu.x = cvtpk(hj[0], hj[1]);                                                \
    hu.y = cvtpk(hj[2], hj[3]);                                                \
    /* exchange h via LDS (parity P) + store to hcat */                        \
    *(uint2*)&hx[P_][s][16 * wv + 4 * g] = hu;                                 \
    *(uint2*)hp = hu;                                                          \
    asm volatile("s_waitcnt lgkmcnt(0)\n\ts_barrier" ::: "memory");            \
    /* read B(h) for next step: k = 4g+(j&3)+16*(j>>2) (+32 for kt1) */        \
    {                                                                          \
      uint2 r00 = *(const uint2*)&hx[P_][s][4 * g];                            \
      uint2 r01 = *(const uint2*)&hx[P_][s][16 + 4 * g];                       \
      uint2 r10 = *(const uint2*)&hx[P_][s][32 + 4 * g];                       \
      uint2 r11 = *(const uint2*)&hx[P_][s][48 + 4 * g];                       \
      U8 t0u, t1u;                                                             \
      t0u.u[0] = r00.x; t0u.u[1] = r00.y; t0u.u[2] = r01.x; t0u.u[3] = r01.y;  \
      t1u.u[0] = r10.x; t1u.u[1] = r10.y; t1u.u[2] = r11.x; t1u.u[3] = r11.y;  \
      bh0 = t0u.v; bh1 = t1u.v;                                                \
    }                                                                          \
    vA += SDIR * II; vB += SDIR * II; hp += SDIR * 128;                        \
  } while (0)

  for (int t = 0; t < TT; t += 2) {
    BODY(t, 0, Xa0, Xb0, Xc0);
    BODY(t + 1, 1, Xa1, Xb1, Xc1);
  }
#undef BODY
}

__global__ __launch_bounds__(256, 1) void scan_kernel(
    const float* __restrict__ x,
    const float* __restrict__ W_ih_f, const float* __restrict__ W_hh_f,
    const float* __restrict__ b_ih_f, const float* __restrict__ b_hh_f,
    const float* __restrict__ W_ih_b, const float* __restrict__ W_hh_b,
    const float* __restrict__ b_ih_b, const float* __restrict__ b_hh_b,
    __hip_bfloat16* __restrict__ hcat) {
  __shared__ short hx[2][16][72];  // [parity][seq][k], stride 72 for banks/align
  const int bid = blockIdx.x;
  if (bid < 16) {
    scan_dir<1>(x, W_ih_f, W_hh_f, b_ih_f, b_hh_f, hcat, 0, bid * 16, hx);
  } else {
    scan_dir<-1>(x, W_ih_b, W_hh_b, b_ih_b, b_hh_b, hcat, 1, (bid - 16) * 16 + 256, hx);
  }
}

// MLP head: out[bt] = sigmoid(W2 . relu(W1 . h128 + b1) + b2), h in bf16.
__global__ __launch_bounds__(256, 2) void mlp_kernel(
    const unsigned* __restrict__ hcat,
    const float* __restrict__ W1, const float* __restrict__ b1,
    const float* __restrict__ W2, const float* __restrict__ b2,
    float* __restrict__ out) {
  __shared__ float4 w1s[64 * 32];
  __shared__ float b1s[64];
  __shared__ float w2s[64];
  __shared__ float b2s;

  const int tid = threadIdx.x;
  const float4* w1g = (const float4*)W1;
  for (int i = tid; i < 64 * 32; i += 256) w1s[i] = w1g[i];
  if (tid < 64) { b1s[tid] = b1[tid]; w2s[tid] = W2[tid]; }
  if (tid == 0) b2s = b2[0];
  __syncthreads();

  const size_t bt = (size_t)blockIdx.x * 256 + tid;
  float4 hreg[32];
  const uint4* hp = (const uint4*)(hcat + bt * 64);
#pragma unroll
  for (int k = 0; k < 16; ++k) {
    uint4 u = hp[k];
    hreg[2 * k].x     = bf16bits_lo(u.x);
    hreg[2 * k].y     = bf16bits_hi(u.x);
    hreg[2 * k].z     = bf16bits_lo(u.y);
    hreg[2 * k].w     = bf16bits_hi(u.y);
    hreg[2 * k + 1].x = bf16bits_lo(u.z);
    hreg[2 * k + 1].y = bf16bits_hi(u.z);
    hreg[2 * k + 1].z = bf16bits_lo(u.w);
    hreg[2 * k + 1].w = bf16bits_hi(u.w);
  }

  float acc2 = b2s;
  for (int o = 0; o < 64; ++o) {
    const float4* wv4 = &w1s[o * 32];
    float4 a; a.x = 0.0f; a.y = 0.0f; a.z = 0.0f; a.w = 0.0f;
#pragma unroll
    for (int k = 0; k < 32; ++k) {
      float4 wv = wv4[k];
      a.x = fmaf(wv.x, hreg[k].x, a.x);
      a.y = fmaf(wv.y, hreg[k].y, a.y);
      a.z = fmaf(wv.z, hreg[k].z, a.z);
      a.w = fmaf(wv.w, hreg[k].w, a.w);
    }
    float z = b1s[o] + (a.x + a.y) + (a.z + a.w);
    z = fmaxf(z, 0.0f);
    acc2 = fmaf(w2s[o], z, acc2);
  }
  out[bt] = sigmoidf_(acc2);
}

extern "C" void kernel_launch(void* const* d_in, const int* in_sizes, int n_in,
                              void* d_out, int out_size, void* d_ws, size_t ws_size,
                              hipStream_t stream) {
  const float* x      = (const float*)d_in[0];
  const float* W_ih_f = (const float*)d_in[1];
  const float* W_hh_f = (const float*)d_in[2];
  const float* b_ih_f = (const float*)d_in[3];
  const float* b_hh_f = (const float*)d_in[4];
  const float* W_ih_b = (const float*)d_in[5];
  const float* W_hh_b = (const float*)d_in[6];
  const float* b_ih_b = (const float*)d_in[7];
  const float* b_hh_b = (const float*)d_in[8];
  const float* W1     = (const float*)d_in[9];
  const float* b1     = (const float*)d_in[10];
  const float* W2     = (const float*)d_in[11];
  const float* b2     = (const float*)d_in[12];
  float* out = (float*)d_out;
  __hip_bfloat16* hcat = (__hip_bfloat16*)d_ws;  // (B, T, 128) bf16 = 196.6 MB

  scan_kernel<<<dim3(32), dim3(256), 0, stream>>>(
      x, W_ih_f, W_hh_f, b_ih_f, b_hh_f, W_ih_b, W_hh_b, b_ih_b, b_hh_b, hcat);

  mlp_kernel<<<dim3(3000), dim3(256), 0, stream>>>((const unsigned*)hcat,
                                                   W1, b1, W2, b2, out);
}